// Round 1
// baseline (693.691 us; speedup 1.0000x reference)
//
#include <hip/hip_runtime.h>
#include <stdint.h>

// Bahdanau additive attention, MI355X (gfx950).
// B=32, T=2048, H=1024, U=1024. All inputs fp32; output context [B,H] fp32.
//
// Pipeline:
//   ws layout: encb (bf16 [M,K], 128 MiB) | Ub (bf16 [K/8][N][8], 2 MiB)
//              | dec_proj (fp32 [B,U]) | score (fp32 [M])
//   1. conv_enc:  enc fp32 -> bf16 (RNE)
//   2. conv_ua:   Ua fp32 -> bf16, permuted to [k/8][u][k%8] (fragment order)
//   3. decproj:   dec_proj = dec_hidden @ Wa  (fp32 exact)
//   4. score_gemm: fused  score[m] += sum_n Va[n]*tanh(acc[m][n]+dec_proj[b][n])
//      128x128x64 tile, mfma_f32_16x16x32_bf16, global_load_lds width 16,
//      LDS layout [k8][row][8] (contiguous per-fragment, dense banks).
//   5. softmax over T per b (in-place on score)
//   6. context:   context[b,h] = sum_t alpha[b,t]*enc_bf16[b,t,h]  (atomicAdd)

#define B_ 32
#define T_ 2048
#define H_ 1024
#define U_ 1024
#define M_ (B_ * T_)

typedef __bf16 bf16x8 __attribute__((ext_vector_type(8)));
typedef float f32x4 __attribute__((ext_vector_type(4)));

__device__ __forceinline__ unsigned f2b(float f) {  // fp32 -> bf16 bits, RNE
  unsigned u = __float_as_uint(f);
  return (u + 0x7FFFu + ((u >> 16) & 1u)) >> 16;
}
__device__ __forceinline__ float b2f(unsigned short u) {
  return __uint_as_float(((unsigned)u) << 16);
}
__device__ __forceinline__ float fast_tanh(float x) {
  // tanh(x) = (e^{2x}-1)/(e^{2x}+1); clamp so exp2 can't overflow.
  float xc = fminf(fmaxf(x, -12.f), 12.f);
  float t = exp2f(xc * 2.885390081777927f);  // 2*log2(e)
  return (t - 1.f) * __builtin_amdgcn_rcpf(t + 1.f);
}

#define AS1 __attribute__((address_space(1)))
#define AS3 __attribute__((address_space(3)))
__device__ __forceinline__ void gld_lds16(const void* g, void* l) {
  __builtin_amdgcn_global_load_lds((AS1 const void*)g, (AS3 void*)l, 16, 0, 0);
}

// ---------------------------------------------------------------- conversions
__global__ __launch_bounds__(256) void conv_enc_k(const float4* __restrict__ in,
                                                  uint4* __restrict__ out) {
  size_t i = (size_t)blockIdx.x * 256 + threadIdx.x;  // 8 floats / thread
  float4 a = in[i * 2], b = in[i * 2 + 1];
  uint4 o;
  o.x = f2b(a.x) | (f2b(a.y) << 16);
  o.y = f2b(a.z) | (f2b(a.w) << 16);
  o.z = f2b(b.x) | (f2b(b.y) << 16);
  o.w = f2b(b.z) | (f2b(b.w) << 16);
  out[i] = o;
}

// Ua [H][U] fp32 -> Ub [(H/8)][U][8] bf16  (B-fragment contiguous order)
__global__ __launch_bounds__(256) void conv_ua_k(const float* __restrict__ in,
                                                 unsigned short* __restrict__ out) {
  int id = blockIdx.x * 256 + threadIdx.x;  // < 1M, coalesced read
  int h = id >> 10, u = id & 1023;
  out[(((size_t)(h >> 3) * U_ + u) << 3) + (h & 7)] = (unsigned short)f2b(in[id]);
}

// ---------------------------------------------------------------- dec_proj
__global__ __launch_bounds__(64) void decproj_k(const float* __restrict__ dh,
                                                const float* __restrict__ Wa,
                                                float* __restrict__ dp) {
  int u = blockIdx.x * 64 + threadIdx.x;
  int b = blockIdx.y;
  const float* d = dh + b * H_;
  const float* w = Wa + u;
  float acc = 0.f;
#pragma unroll 8
  for (int h = 0; h < H_; ++h) acc = fmaf(d[h], w[(size_t)h * U_], acc);
  dp[b * U_ + u] = acc;
}

// ---------------------------------------------------------------- fused GEMM
// grid 4096: mtile = bx & 511 (fast), ntile = bx >> 9 (slow) -> each N-pass
// streams encb once; passes 2..8 hit L3 (encb = 128 MiB < 256 MiB).
__global__ __launch_bounds__(256, 2) void score_gemm_k(
    const unsigned short* __restrict__ encb,  // [M][K] bf16
    const unsigned short* __restrict__ Ub,    // [K/8][N][8] bf16
    const float* __restrict__ dp,             // [B][U]
    const float* __restrict__ Va,             // [U]
    float* __restrict__ score)                // [M], pre-zeroed
{
  __shared__ alignas(16) unsigned short As[8][128][8];  // [k8][m][j] 16 KiB
  __shared__ alignas(16) unsigned short Bs[8][128][8];  // [k8][n][j] 16 KiB

  const int bx = blockIdx.x;
  const int mtile = bx & 511, ntile = bx >> 9;
  const int m0 = mtile << 7, n0 = ntile << 7;
  const int tid = threadIdx.x;
  const int wv = tid >> 6, ln = tid & 63;
  const int wm = wv & 1, wn = wv >> 1;      // 2x2 waves -> 64x64 each
  const int quad = ln >> 4, l16 = ln & 15;

  f32x4 acc[4][4];
  const f32x4 zero = {0.f, 0.f, 0.f, 0.f};
#pragma unroll
  for (int i = 0; i < 4; ++i)
#pragma unroll
    for (int j = 0; j < 4; ++j) acc[i][j] = zero;

  for (int k0 = 0; k0 < H_; k0 += 64) {
    __syncthreads();  // previous tile fully consumed
#pragma unroll
    for (int c = 0; c < 4; ++c) {  // 4 A-chunks + 4 B-chunks per wave
      int chunk = (wv << 2) + c;   // 0..15
      int k8 = chunk >> 1, half = chunk & 1;
      const unsigned short* ga =
          encb + (size_t)(m0 + (half << 6) + ln) * H_ + k0 + (k8 << 3);
      gld_lds16(ga, &As[k8][half << 6][0]);
      const unsigned short* gb =
          Ub + (((size_t)((k0 >> 3) + k8) * U_) + n0 + (half << 6) + ln) * 8;
      gld_lds16(gb, &Bs[k8][half << 6][0]);
    }
    __syncthreads();  // vmcnt(0) drain -> LDS visible

#pragma unroll
    for (int kk = 0; kk < 2; ++kk) {  // two k=32 MFMA steps
      int k8b = (kk << 2) + quad;
      bf16x8 af[4], bf[4];
#pragma unroll
      for (int mt = 0; mt < 4; ++mt)
        af[mt] = *(const bf16x8*)&As[k8b][(wm << 6) + (mt << 4) + l16][0];
#pragma unroll
      for (int nt = 0; nt < 4; ++nt)
        bf[nt] = *(const bf16x8*)&Bs[k8b][(wn << 6) + (nt << 4) + l16][0];
#pragma unroll
      for (int mt = 0; mt < 4; ++mt)
#pragma unroll
        for (int nt = 0; nt < 4; ++nt)
          acc[mt][nt] = __builtin_amdgcn_mfma_f32_16x16x32_bf16(
              af[mt], bf[nt], acc[mt][nt], 0, 0, 0);
    }
  }

  // Epilogue: tanh(acc + dec_proj) * Va, reduce over cols, atomicAdd rows.
  // C/D layout: col = l16, row = quad*4 + r  (per 16x16 tile).
  const int bq = m0 >> 11;  // b index (tile never straddles b: 2048 % 128 == 0)
  float va[4], dpv[4];
#pragma unroll
  for (int nt = 0; nt < 4; ++nt) {
    int col = n0 + (wn << 6) + (nt << 4) + l16;
    va[nt] = Va[col];
    dpv[nt] = dp[bq * U_ + col];
  }
#pragma unroll
  for (int mt = 0; mt < 4; ++mt) {
#pragma unroll
    for (int r = 0; r < 4; ++r) {
      float v = 0.f;
#pragma unroll
      for (int nt = 0; nt < 4; ++nt)
        v += fast_tanh(acc[mt][nt][r] + dpv[nt]) * va[nt];
      v += __shfl_xor(v, 1);
      v += __shfl_xor(v, 2);
      v += __shfl_xor(v, 4);
      v += __shfl_xor(v, 8);  // sum over the 16 cols held in this quad
      if (l16 == 0)
        atomicAdd(&score[m0 + (wm << 6) + (mt << 4) + (quad << 2) + r], v);
    }
  }
}

// ---------------------------------------------------------------- softmax
__global__ __launch_bounds__(256) void softmax_k(float* __restrict__ score) {
  const int b = blockIdx.x, tid = threadIdx.x;
  float4* s4 = (float4*)(score + b * T_);
  __shared__ float red[4];
  float4 v0 = s4[tid * 2], v1 = s4[tid * 2 + 1];
  float m = fmaxf(fmaxf(fmaxf(v0.x, v0.y), fmaxf(v0.z, v0.w)),
                  fmaxf(fmaxf(v1.x, v1.y), fmaxf(v1.z, v1.w)));
#pragma unroll
  for (int off = 32; off >= 1; off >>= 1) m = fmaxf(m, __shfl_xor(m, off));
  if ((tid & 63) == 0) red[tid >> 6] = m;
  __syncthreads();
  m = fmaxf(fmaxf(red[0], red[1]), fmaxf(red[2], red[3]));
  __syncthreads();
  const float l2e = 1.4426950408889634f;
  float e[8];
  e[0] = exp2f((v0.x - m) * l2e); e[1] = exp2f((v0.y - m) * l2e);
  e[2] = exp2f((v0.z - m) * l2e); e[3] = exp2f((v0.w - m) * l2e);
  e[4] = exp2f((v1.x - m) * l2e); e[5] = exp2f((v1.y - m) * l2e);
  e[6] = exp2f((v1.z - m) * l2e); e[7] = exp2f((v1.w - m) * l2e);
  float sum = e[0] + e[1] + e[2] + e[3] + e[4] + e[5] + e[6] + e[7];
#pragma unroll
  for (int off = 32; off >= 1; off >>= 1) sum += __shfl_xor(sum, off);
  if ((tid & 63) == 0) red[tid >> 6] = sum;
  __syncthreads();
  float inv = 1.f / (red[0] + red[1] + red[2] + red[3]);
  v0.x = e[0] * inv; v0.y = e[1] * inv; v0.z = e[2] * inv; v0.w = e[3] * inv;
  v1.x = e[4] * inv; v1.y = e[5] * inv; v1.z = e[6] * inv; v1.w = e[7] * inv;
  s4[tid * 2] = v0;
  s4[tid * 2 + 1] = v1;
}

// ---------------------------------------------------------------- context
__global__ __launch_bounds__(256) void context_k(const unsigned short* __restrict__ encb,
                                                 const float* __restrict__ alpha,
                                                 float* __restrict__ out) {
  const int b = blockIdx.y, tch = blockIdx.x;
  const int h4 = threadIdx.x << 2;  // 4 h per thread -> 1024 h per block
  const unsigned short* base = encb + (size_t)b * T_ * H_ + h4;
  const float* al = alpha + b * T_ + tch * 256;
  float a0 = 0.f, a1 = 0.f, a2 = 0.f, a3 = 0.f;
  for (int t = 0; t < 256; ++t) {
    float a = al[t];  // uniform -> scalar load
    ushort4 e = *(const ushort4*)(base + (size_t)(tch * 256 + t) * H_);
    a0 = fmaf(a, b2f(e.x), a0);
    a1 = fmaf(a, b2f(e.y), a1);
    a2 = fmaf(a, b2f(e.z), a2);
    a3 = fmaf(a, b2f(e.w), a3);
  }
  float* o = out + b * H_ + h4;
  atomicAdd(o + 0, a0); atomicAdd(o + 1, a1);
  atomicAdd(o + 2, a2); atomicAdd(o + 3, a3);
}

// ---------------------------------------------------------------- launch
extern "C" void kernel_launch(void* const* d_in, const int* in_sizes, int n_in,
                              void* d_out, int out_size, void* d_ws, size_t ws_size,
                              hipStream_t stream) {
  const float* enc = (const float*)d_in[0];
  const float* dh  = (const float*)d_in[1];
  const float* Wa  = (const float*)d_in[2];
  const float* Ua  = (const float*)d_in[3];
  const float* Va  = (const float*)d_in[4];
  float* out = (float*)d_out;

  char* ws = (char*)d_ws;
  unsigned short* encb = (unsigned short*)ws;                         // 128 MiB
  unsigned short* Ub   = (unsigned short*)(ws + 134217728);           // 2 MiB
  float* dp    = (float*)(ws + 134217728 + 2097152);                  // 128 KiB
  float* score = (float*)(ws + 134217728 + 2097152 + 131072);         // 256 KiB

  hipMemsetAsync(score, 0, M_ * sizeof(float), stream);
  hipMemsetAsync(d_out, 0, B_ * H_ * sizeof(float), stream);

  conv_enc_k<<<32768, 256, 0, stream>>>((const float4*)enc, (uint4*)encb);
  conv_ua_k<<<4096, 256, 0, stream>>>(Ua, Ub);
  decproj_k<<<dim3(16, 32), 64, 0, stream>>>(dh, Wa, dp);
  score_gemm_k<<<4096, 256, 0, stream>>>(encb, Ub, dp, Va, score);
  softmax_k<<<32, 256, 0, stream>>>(score);
  context_k<<<dim3(8, 32), 256, 0, stream>>>(encb, score, out);
}

// Round 2
// 626.892 us; speedup vs baseline: 1.1066x; 1.1066x over previous
//
#include <hip/hip_runtime.h>
#include <stdint.h>

// Bahdanau additive attention, MI355X (gfx950).
// B=32, T=2048, H=1024, U=1024. All inputs fp32; output context [B,H] fp32.
//
// R2 changes vs R1:
//  - encA packed [mtile(512)][k8(128)][ml(128)][8] so GEMM A-staging is dense
//    1 KiB/gld_lds (was 64x16B gather at 2KB stride).
//  - conv_enc: 64B/lane full-cacheline reads, dense packed 16B writes.
//  - score_gemm epilogue: LDS reduce (stride-33 pad) instead of 64 shuffles.
//  - context: reads packed layout (contiguous 1KB/thread streams), 512 blocks.
//  - decproj: K-split x4 with atomics for parallelism.

#define B_ 32
#define T_ 2048
#define H_ 1024
#define U_ 1024
#define M_ (B_ * T_)

typedef __bf16 bf16x8 __attribute__((ext_vector_type(8)));
typedef float f32x4 __attribute__((ext_vector_type(4)));

__device__ __forceinline__ unsigned f2b(float f) {  // fp32 -> bf16 bits, RNE
  unsigned u = __float_as_uint(f);
  return (u + 0x7FFFu + ((u >> 16) & 1u)) >> 16;
}
__device__ __forceinline__ float b2f(unsigned short u) {
  return __uint_as_float(((unsigned)u) << 16);
}
__device__ __forceinline__ float fast_tanh(float x) {
  float xc = fminf(fmaxf(x, -12.f), 12.f);
  float t = exp2f(xc * 2.885390081777927f);  // 2*log2(e)
  return (t - 1.f) * __builtin_amdgcn_rcpf(t + 1.f);
}

#define AS1 __attribute__((address_space(1)))
#define AS3 __attribute__((address_space(3)))
__device__ __forceinline__ void gld_lds16(const void* g, void* l) {
  __builtin_amdgcn_global_load_lds((AS1 const void*)g, (AS3 void*)l, 16, 0, 0);
}

// ------------------------------------------------------------- conv_enc
// enc fp32 [M][K] -> encA bf16 packed [mt][k8][ml][8]:
//   index(m,k) = ((((m>>7)*128) + (k>>3))*128 + (m&127))*8 + (k&7)
// Thread: one row-chunk of 16 k (64B read, full cachelines), 2x16B packed writes.
__global__ __launch_bounds__(256) void conv_enc_k(const float4* __restrict__ in,
                                                  uint4* __restrict__ outA) {
  const int ml = threadIdx.x & 127, kh = threadIdx.x >> 7;
  const int bk = blockIdx.x;          // 0..31
  const int mt = blockIdx.y;          // 0..511
  const int kc = bk * 2 + kh;         // 16-float chunk id, 0..63
  const float4* src = in + ((size_t)(mt * 128 + ml) * 256) + kc * 4;
  float4 a = src[0], b = src[1], c = src[2], d = src[3];
  uint4 o0, o1;
  o0.x = f2b(a.x) | (f2b(a.y) << 16);
  o0.y = f2b(a.z) | (f2b(a.w) << 16);
  o0.z = f2b(b.x) | (f2b(b.y) << 16);
  o0.w = f2b(b.z) | (f2b(b.w) << 16);
  o1.x = f2b(c.x) | (f2b(c.y) << 16);
  o1.y = f2b(c.z) | (f2b(c.w) << 16);
  o1.z = f2b(d.x) | (f2b(d.y) << 16);
  o1.w = f2b(d.z) | (f2b(d.w) << 16);
  const int k8 = kc * 2;
  outA[((size_t)mt * 128 + k8) * 128 + ml] = o0;
  outA[((size_t)mt * 128 + k8 + 1) * 128 + ml] = o1;
}

// Ua [H][U] fp32 -> Ub [(H/8)][U][8] bf16  (B-fragment contiguous order)
__global__ __launch_bounds__(256) void conv_ua_k(const float* __restrict__ in,
                                                 unsigned short* __restrict__ out) {
  int id = blockIdx.x * 256 + threadIdx.x;
  int h = id >> 10, u = id & 1023;
  out[(((size_t)(h >> 3) * U_ + u) << 3) + (h & 7)] = (unsigned short)f2b(in[id]);
}

// ------------------------------------------------------------- dec_proj
// dp[b][u] += sum over 256-h chunk; grid (4 u-chunks, 32 b, 4 h-chunks).
__global__ __launch_bounds__(256) void decproj_k(const float* __restrict__ dh,
                                                 const float* __restrict__ Wa,
                                                 float* __restrict__ dp) {
  const int u = blockIdx.x * 256 + threadIdx.x;
  const int b = blockIdx.y, hz = blockIdx.z;
  const float* d = dh + b * H_ + hz * 256;
  const float* w = Wa + (size_t)(hz * 256) * U_ + u;
  float a0 = 0.f, a1 = 0.f, a2 = 0.f, a3 = 0.f;
#pragma unroll 4
  for (int h = 0; h < 256; h += 4) {
    a0 = fmaf(d[h + 0], w[(size_t)(h + 0) * U_], a0);
    a1 = fmaf(d[h + 1], w[(size_t)(h + 1) * U_], a1);
    a2 = fmaf(d[h + 2], w[(size_t)(h + 2) * U_], a2);
    a3 = fmaf(d[h + 3], w[(size_t)(h + 3) * U_], a3);
  }
  atomicAdd(&dp[b * U_ + u], (a0 + a1) + (a2 + a3));
}

// ------------------------------------------------------------- fused GEMM
// grid 4096: mtile = bx & 511 (fast), ntile = bx >> 9 (slow).
__global__ __launch_bounds__(256, 2) void score_gemm_k(
    const unsigned short* __restrict__ encA,  // packed [mt][k8][ml][8]
    const unsigned short* __restrict__ Ub,    // [k8][N][8]
    const float* __restrict__ dp,             // [B][U]
    const float* __restrict__ Va,             // [U]
    float* __restrict__ score)                // [M], pre-zeroed
{
  __shared__ union {
    struct {
      alignas(16) unsigned short As[8][128][8];  // [k8][m][j] 16 KiB
      alignas(16) unsigned short Bs[8][128][8];  // [k8][n][j] 16 KiB
    } t;
    float sred[128 * 33];  // epilogue scratch, stride-33 pad (16.5 KiB)
  } sm;

  const int bx = blockIdx.x;
  const int mtile = bx & 511, ntile = bx >> 9;
  const int m0 = mtile << 7, n0 = ntile << 7;
  const int tid = threadIdx.x;
  const int wv = tid >> 6, ln = tid & 63;
  const int wm = wv & 1, wn = wv >> 1;
  const int quad = ln >> 4, l16 = ln & 15;

  f32x4 acc[4][4];
  const f32x4 zero = {0.f, 0.f, 0.f, 0.f};
#pragma unroll
  for (int i = 0; i < 4; ++i)
#pragma unroll
    for (int j = 0; j < 4; ++j) acc[i][j] = zero;

  const unsigned short* encT = encA + (size_t)mtile * (128 * 128 * 8);

  for (int k0 = 0; k0 < H_; k0 += 64) {
    __syncthreads();
#pragma unroll
    for (int c = 0; c < 4; ++c) {
      int chunk = (wv << 2) + c;  // 0..15
      int k8 = chunk >> 1, half = chunk & 1;
      // A: packed, dense 1 KiB per wave-instruction
      const unsigned short* ga =
          encT + (((size_t)((k0 >> 3) + k8) * 128) + (half << 6) + ln) * 8;
      gld_lds16(ga, &sm.t.As[k8][half << 6][0]);
      const unsigned short* gb =
          Ub + (((size_t)((k0 >> 3) + k8) * U_) + n0 + (half << 6) + ln) * 8;
      gld_lds16(gb, &sm.t.Bs[k8][half << 6][0]);
    }
    __syncthreads();

#pragma unroll
    for (int kk = 0; kk < 2; ++kk) {
      int k8b = (kk << 2) + quad;
      bf16x8 af[4], bf[4];
#pragma unroll
      for (int mt = 0; mt < 4; ++mt)
        af[mt] = *(const bf16x8*)&sm.t.As[k8b][(wm << 6) + (mt << 4) + l16][0];
#pragma unroll
      for (int nt = 0; nt < 4; ++nt)
        bf[nt] = *(const bf16x8*)&sm.t.Bs[k8b][(wn << 6) + (nt << 4) + l16][0];
#pragma unroll
      for (int mt = 0; mt < 4; ++mt)
#pragma unroll
        for (int nt = 0; nt < 4; ++nt)
          acc[mt][nt] = __builtin_amdgcn_mfma_f32_16x16x32_bf16(
              af[mt], bf[nt], acc[mt][nt], 0, 0, 0);
    }
  }

  // Epilogue: v = sum_nt tanh(acc+dp)*Va, LDS reduce over 32 col-groups.
  // C/D layout: col = l16, row = quad*4 + r  (per 16x16 tile).
  const int bq = m0 >> 11;  // batch (tile never straddles b)
  float va[4], dpv[4];
#pragma unroll
  for (int nt = 0; nt < 4; ++nt) {
    int col = n0 + (wn << 6) + (nt << 4) + l16;
    va[nt] = Va[col];
    dpv[nt] = dp[bq * U_ + col];
  }
  __syncthreads();  // all LDS reads of As/Bs done; reuse as sred
#pragma unroll
  for (int mt = 0; mt < 4; ++mt) {
#pragma unroll
    for (int r = 0; r < 4; ++r) {
      float v = 0.f;
#pragma unroll
      for (int nt = 0; nt < 4; ++nt)
        v += fast_tanh(acc[mt][nt][r] + dpv[nt]) * va[nt];
      int row = (wm << 6) + (mt << 4) + (quad << 2) + r;
      sm.sred[row * 33 + (wn << 4) + l16] = v;
    }
  }
  __syncthreads();
  if (tid < 128) {
    const float* p = &sm.sred[tid * 33];
    float s = 0.f;
#pragma unroll
    for (int j = 0; j < 32; ++j) s += p[j];
    atomicAdd(&score[m0 + tid], s);
  }
}

// ------------------------------------------------------------- softmax
__global__ __launch_bounds__(256) void softmax_k(float* __restrict__ score) {
  const int b = blockIdx.x, tid = threadIdx.x;
  float4* s4 = (float4*)(score + b * T_);
  __shared__ float red[4];
  float4 v0 = s4[tid * 2], v1 = s4[tid * 2 + 1];
  float m = fmaxf(fmaxf(fmaxf(v0.x, v0.y), fmaxf(v0.z, v0.w)),
                  fmaxf(fmaxf(v1.x, v1.y), fmaxf(v1.z, v1.w)));
#pragma unroll
  for (int off = 32; off >= 1; off >>= 1) m = fmaxf(m, __shfl_xor(m, off));
  if ((tid & 63) == 0) red[tid >> 6] = m;
  __syncthreads();
  m = fmaxf(fmaxf(red[0], red[1]), fmaxf(red[2], red[3]));
  __syncthreads();
  const float l2e = 1.4426950408889634f;
  float e[8];
  e[0] = exp2f((v0.x - m) * l2e); e[1] = exp2f((v0.y - m) * l2e);
  e[2] = exp2f((v0.z - m) * l2e); e[3] = exp2f((v0.w - m) * l2e);
  e[4] = exp2f((v1.x - m) * l2e); e[5] = exp2f((v1.y - m) * l2e);
  e[6] = exp2f((v1.z - m) * l2e); e[7] = exp2f((v1.w - m) * l2e);
  float sum = (e[0] + e[1]) + (e[2] + e[3]) + (e[4] + e[5]) + (e[6] + e[7]);
#pragma unroll
  for (int off = 32; off >= 1; off >>= 1) sum += __shfl_xor(sum, off);
  if ((tid & 63) == 0) red[tid >> 6] = sum;
  __syncthreads();
  float inv = 1.f / (red[0] + red[1] + red[2] + red[3]);
  v0.x = e[0] * inv; v0.y = e[1] * inv; v0.z = e[2] * inv; v0.w = e[3] * inv;
  v1.x = e[4] * inv; v1.y = e[5] * inv; v1.z = e[6] * inv; v1.w = e[7] * inv;
  s4[tid * 2] = v0;
  s4[tid * 2 + 1] = v1;
}

// ------------------------------------------------------------- context
// context[b,h] = sum_t alpha[b,t] * enc[b,t,h], reading packed encA.
// grid (16 t-chunks, 32 b), block 256 = (tx:128 h-groups) x (th:2 t-halves).
// Per thread: 64 contiguous 16B loads (1 KiB stream).
__global__ __launch_bounds__(256) void context_k(const uint4* __restrict__ encA,
                                                 const float* __restrict__ alpha,
                                                 float* __restrict__ out) {
  const int tx = threadIdx.x & 127, th = threadIdx.x >> 7;
  const int b = blockIdx.y, bt = blockIdx.x;
  const int mt = b * 16 + bt;            // packed row-tile (t-chunk 128)
  const uint4* base = encA + ((size_t)mt * 128 + tx) * 128 + th * 64;
  const float* al = alpha + b * T_ + bt * 128 + th * 64;
  float a[8];
#pragma unroll
  for (int j = 0; j < 8; ++j) a[j] = 0.f;
#pragma unroll 4
  for (int i = 0; i < 64; ++i) {
    float w = al[i];
    uint4 e = base[i];
    a[0] = fmaf(w, b2f((unsigned short)e.x), a[0]);
    a[1] = fmaf(w, b2f((unsigned short)(e.x >> 16)), a[1]);
    a[2] = fmaf(w, b2f((unsigned short)e.y), a[2]);
    a[3] = fmaf(w, b2f((unsigned short)(e.y >> 16)), a[3]);
    a[4] = fmaf(w, b2f((unsigned short)e.z), a[4]);
    a[5] = fmaf(w, b2f((unsigned short)(e.z >> 16)), a[5]);
    a[6] = fmaf(w, b2f((unsigned short)e.w), a[6]);
    a[7] = fmaf(w, b2f((unsigned short)(e.w >> 16)), a[7]);
  }
  __shared__ float cred[2][128][8];
#pragma unroll
  for (int j = 0; j < 8; ++j) cred[th][tx][j] = a[j];
  __syncthreads();
  if (th == 0) {
#pragma unroll
    for (int j = 0; j < 8; ++j)
      atomicAdd(&out[b * H_ + tx * 8 + j], cred[0][tx][j] + cred[1][tx][j]);
  }
}

// ------------------------------------------------------------- launch
extern "C" void kernel_launch(void* const* d_in, const int* in_sizes, int n_in,
                              void* d_out, int out_size, void* d_ws, size_t ws_size,
                              hipStream_t stream) {
  const float* enc = (const float*)d_in[0];
  const float* dh  = (const float*)d_in[1];
  const float* Wa  = (const float*)d_in[2];
  const float* Ua  = (const float*)d_in[3];
  const float* Va  = (const float*)d_in[4];

  char* ws = (char*)d_ws;
  unsigned short* encA = (unsigned short*)ws;                          // 128 MiB
  unsigned short* Ub   = (unsigned short*)(ws + 134217728);            // 2 MiB
  float* dp    = (float*)(ws + 134217728 + 2097152);                   // 128 KiB
  float* score = (float*)(ws + 134217728 + 2097152 + 131072);          // 256 KiB

  hipMemsetAsync(dp, 0, B_ * U_ * sizeof(float), stream);
  hipMemsetAsync(score, 0, M_ * sizeof(float), stream);
  hipMemsetAsync(d_out, 0, B_ * H_ * sizeof(float), stream);

  conv_enc_k<<<dim3(32, 512), 256, 0, stream>>>((const float4*)enc, (uint4*)encA);
  conv_ua_k<<<4096, 256, 0, stream>>>(Ua, Ub);
  decproj_k<<<dim3(4, 32, 4), 256, 0, stream>>>(dh, Wa, dp);
  score_gemm_k<<<4096, 256, 0, stream>>>(encA, Ub, dp, Va, score);
  softmax_k<<<32, 256, 0, stream>>>(score);
  context_k<<<dim3(16, 32), 256, 0, stream>>>((const uint4*)encA, score, (float*)d_out);
}

// Round 3
// 586.020 us; speedup vs baseline: 1.1837x; 1.0697x over previous
//
#include <hip/hip_runtime.h>
#include <stdint.h>

// Bahdanau additive attention, MI355X (gfx950).
// B=32, T=2048, H=1024, U=1024. All inputs fp32; output context [B,H] fp32.
//
// R3 changes vs R2:
//  - conv_enc: LDS-staged transpose. Reads are fully sequential/coalesced
//    (32B/lane), writes are 256B-granular packed. LDS stride-17 uint4 layout
//    gives bank-quad (k8+r)%8 -> provably uniform, conflict-free both phases.
//  - No memsets, no global atomics: decproj -> 4 private slabs (summed in
//    gemm epilogue); score_gemm -> 8 per-ntile slabs (summed in softmax);
//    context -> 16 per-tchunk slabs + tiny final reduce kernel.
//  - ws overlays: alpha reuses dp4 region, ctx partials reuse score8 region.

#define B_ 32
#define T_ 2048
#define H_ 1024
#define U_ 1024
#define M_ (B_ * T_)

typedef __bf16 bf16x8 __attribute__((ext_vector_type(8)));
typedef float f32x4 __attribute__((ext_vector_type(4)));

__device__ __forceinline__ unsigned f2b(float f) {  // fp32 -> bf16 bits, RNE
  unsigned u = __float_as_uint(f);
  return (u + 0x7FFFu + ((u >> 16) & 1u)) >> 16;
}
__device__ __forceinline__ float b2f(unsigned short u) {
  return __uint_as_float(((unsigned)u) << 16);
}
__device__ __forceinline__ float fast_tanh(float x) {
  float xc = fminf(fmaxf(x, -12.f), 12.f);
  float t = exp2f(xc * 2.885390081777927f);  // 2*log2(e)
  return (t - 1.f) * __builtin_amdgcn_rcpf(t + 1.f);
}

#define AS1 __attribute__((address_space(1)))
#define AS3 __attribute__((address_space(3)))
__device__ __forceinline__ void gld_lds16(const void* g, void* l) {
  __builtin_amdgcn_global_load_lds((AS1 const void*)g, (AS3 void*)l, 16, 0, 0);
}

// ------------------------------------------------------------- conv_enc
// enc fp32 [M][1024] -> encA bf16 packed [mt][k8][ml][8] via LDS transpose.
// Block: 16 rows (one band). Read phase: thread reads 32B contiguous
// (2x float4), whole block walks a 64 KiB contiguous region. LDS uint4
// L4[k8*17 + r]: stride 17 => bank-quad (k8+r)%8, uniform in both phases.
// Write phase: 4 x 256B segments per wave instruction.
__global__ __launch_bounds__(256) void conv_enc_k(const float4* __restrict__ in,
                                                  uint4* __restrict__ outA) {
  __shared__ uint4 L4[128 * 17];
  const int tx = threadIdx.x;
  const int band = blockIdx.x;      // 0..4095
  const int mt = band >> 3;
  const int R = (band & 7) << 4;    // ml base within 128-row tile
  const float4* src = in + (size_t)band * 4096;  // 16 rows * 256 float4
#pragma unroll
  for (int i = 0; i < 8; ++i) {
    int p = i * 256 + tx;           // pair index: row r, k8 chunk pc
    int r = p >> 7, pc = p & 127;
    float4 a = src[r * 256 + pc * 2];
    float4 b = src[r * 256 + pc * 2 + 1];
    uint4 o;
    o.x = f2b(a.x) | (f2b(a.y) << 16);
    o.y = f2b(a.z) | (f2b(a.w) << 16);
    o.z = f2b(b.x) | (f2b(b.y) << 16);
    o.w = f2b(b.z) | (f2b(b.w) << 16);
    L4[pc * 17 + r] = o;
  }
  __syncthreads();
  const int r2 = tx & 15, kq = (tx >> 4) & 3, w = tx >> 6;
#pragma unroll
  for (int j = 0; j < 8; ++j) {
    int k8 = j * 16 + w * 4 + kq;
    outA[((size_t)mt * 128 + k8) * 128 + R + r2] = L4[k8 * 17 + r2];
  }
}

// Ua [H][U] fp32 -> Ub [(H/8)][U][8] bf16  (B-fragment contiguous order)
__global__ __launch_bounds__(256) void conv_ua_k(const float* __restrict__ in,
                                                 unsigned short* __restrict__ out) {
  int id = blockIdx.x * 256 + threadIdx.x;
  int h = id >> 10, u = id & 1023;
  out[(((size_t)(h >> 3) * U_ + u) << 3) + (h & 7)] = (unsigned short)f2b(in[id]);
}

// ------------------------------------------------------------- dec_proj
// dp4[hz][b][u] = partial over 256-h chunk; no atomics, no memset.
__global__ __launch_bounds__(256) void decproj_k(const float* __restrict__ dh,
                                                 const float* __restrict__ Wa,
                                                 float* __restrict__ dp4) {
  const int u = blockIdx.x * 256 + threadIdx.x;
  const int b = blockIdx.y, hz = blockIdx.z;
  const float* d = dh + b * H_ + hz * 256;
  const float* w = Wa + (size_t)(hz * 256) * U_ + u;
  float a0 = 0.f, a1 = 0.f, a2 = 0.f, a3 = 0.f;
#pragma unroll 4
  for (int h = 0; h < 256; h += 4) {
    a0 = fmaf(d[h + 0], w[(size_t)(h + 0) * U_], a0);
    a1 = fmaf(d[h + 1], w[(size_t)(h + 1) * U_], a1);
    a2 = fmaf(d[h + 2], w[(size_t)(h + 2) * U_], a2);
    a3 = fmaf(d[h + 3], w[(size_t)(h + 3) * U_], a3);
  }
  dp4[((hz * B_ + b) * U_) + u] = (a0 + a1) + (a2 + a3);
}

// ------------------------------------------------------------- fused GEMM
// grid 4096: mtile = bx & 511 (fast), ntile = bx >> 9 (slow).
// Writes per-ntile slab score8[ntile][m] (no atomics).
__global__ __launch_bounds__(256, 2) void score_gemm_k(
    const unsigned short* __restrict__ encA,  // packed [mt][k8][ml][8]
    const unsigned short* __restrict__ Ub,    // [k8][N][8]
    const float* __restrict__ dp4,            // [4][B][U]
    const float* __restrict__ Va,             // [U]
    float* __restrict__ score8)               // [8][M]
{
  __shared__ union {
    struct {
      alignas(16) unsigned short As[8][128][8];  // [k8][m][j] 16 KiB
      alignas(16) unsigned short Bs[8][128][8];  // [k8][n][j] 16 KiB
    } t;
    float sred[128 * 33];  // epilogue scratch, stride-33 pad
  } sm;

  const int bx = blockIdx.x;
  const int mtile = bx & 511, ntile = bx >> 9;
  const int m0 = mtile << 7, n0 = ntile << 7;
  const int tid = threadIdx.x;
  const int wv = tid >> 6, ln = tid & 63;
  const int wm = wv & 1, wn = wv >> 1;
  const int quad = ln >> 4, l16 = ln & 15;

  f32x4 acc[4][4];
  const f32x4 zero = {0.f, 0.f, 0.f, 0.f};
#pragma unroll
  for (int i = 0; i < 4; ++i)
#pragma unroll
    for (int j = 0; j < 4; ++j) acc[i][j] = zero;

  const unsigned short* encT = encA + (size_t)mtile * (128 * 128 * 8);

  for (int k0 = 0; k0 < H_; k0 += 64) {
    __syncthreads();
#pragma unroll
    for (int c = 0; c < 4; ++c) {
      int chunk = (wv << 2) + c;  // 0..15
      int k8 = chunk >> 1, half = chunk & 1;
      const unsigned short* ga =
          encT + (((size_t)((k0 >> 3) + k8) * 128) + (half << 6) + ln) * 8;
      gld_lds16(ga, &sm.t.As[k8][half << 6][0]);
      const unsigned short* gb =
          Ub + (((size_t)((k0 >> 3) + k8) * U_) + n0 + (half << 6) + ln) * 8;
      gld_lds16(gb, &sm.t.Bs[k8][half << 6][0]);
    }
    __syncthreads();

#pragma unroll
    for (int kk = 0; kk < 2; ++kk) {
      int k8b = (kk << 2) + quad;
      bf16x8 af[4], bf[4];
#pragma unroll
      for (int mt = 0; mt < 4; ++mt)
        af[mt] = *(const bf16x8*)&sm.t.As[k8b][(wm << 6) + (mt << 4) + l16][0];
#pragma unroll
      for (int nt = 0; nt < 4; ++nt)
        bf[nt] = *(const bf16x8*)&sm.t.Bs[k8b][(wn << 6) + (nt << 4) + l16][0];
#pragma unroll
      for (int mt = 0; mt < 4; ++mt)
#pragma unroll
        for (int nt = 0; nt < 4; ++nt)
          acc[mt][nt] = __builtin_amdgcn_mfma_f32_16x16x32_bf16(
              af[mt], bf[nt], acc[mt][nt], 0, 0, 0);
    }
  }

  // Epilogue: v = sum_nt tanh(acc + dp) * Va; LDS reduce over 32 col-groups.
  // C/D layout: col = l16, row = quad*4 + r.
  const int bq = m0 >> 11;  // batch (tile never straddles b)
  float va[4], dpv[4];
#pragma unroll
  for (int nt = 0; nt < 4; ++nt) {
    int col = n0 + (wn << 6) + (nt << 4) + l16;
    va[nt] = Va[col];
    dpv[nt] = dp4[bq * U_ + col] + dp4[B_ * U_ + bq * U_ + col] +
              dp4[2 * B_ * U_ + bq * U_ + col] + dp4[3 * B_ * U_ + bq * U_ + col];
  }
  __syncthreads();  // LDS tile reads done; reuse as sred
#pragma unroll
  for (int mt = 0; mt < 4; ++mt) {
#pragma unroll
    for (int r = 0; r < 4; ++r) {
      float v = 0.f;
#pragma unroll
      for (int nt = 0; nt < 4; ++nt)
        v += fast_tanh(acc[mt][nt][r] + dpv[nt]) * va[nt];
      int row = (wm << 6) + (mt << 4) + (quad << 2) + r;
      sm.sred[row * 33 + (wn << 4) + l16] = v;
    }
  }
  __syncthreads();
  if (tid < 128) {
    const float* p = &sm.sred[tid * 33];
    float s = 0.f;
#pragma unroll
    for (int j = 0; j < 32; ++j) s += p[j];
    score8[(size_t)ntile * M_ + m0 + tid] = s;
  }
}

// ------------------------------------------------------------- softmax
// Sums the 8 ntile slabs, then softmax over T per b; writes alpha.
__global__ __launch_bounds__(256) void softmax_k(const float* __restrict__ score8,
                                                 float* __restrict__ alpha) {
  const int b = blockIdx.x, tid = threadIdx.x;
  __shared__ float red[4];
  float4 v0 = {0.f, 0.f, 0.f, 0.f}, v1 = {0.f, 0.f, 0.f, 0.f};
#pragma unroll
  for (int k = 0; k < 8; ++k) {
    const float4* p = (const float4*)(score8 + (size_t)k * M_ + b * T_);
    float4 x0 = p[tid * 2], x1 = p[tid * 2 + 1];
    v0.x += x0.x; v0.y += x0.y; v0.z += x0.z; v0.w += x0.w;
    v1.x += x1.x; v1.y += x1.y; v1.z += x1.z; v1.w += x1.w;
  }
  float m = fmaxf(fmaxf(fmaxf(v0.x, v0.y), fmaxf(v0.z, v0.w)),
                  fmaxf(fmaxf(v1.x, v1.y), fmaxf(v1.z, v1.w)));
#pragma unroll
  for (int off = 32; off >= 1; off >>= 1) m = fmaxf(m, __shfl_xor(m, off));
  if ((tid & 63) == 0) red[tid >> 6] = m;
  __syncthreads();
  m = fmaxf(fmaxf(red[0], red[1]), fmaxf(red[2], red[3]));
  __syncthreads();
  const float l2e = 1.4426950408889634f;
  float e[8];
  e[0] = exp2f((v0.x - m) * l2e); e[1] = exp2f((v0.y - m) * l2e);
  e[2] = exp2f((v0.z - m) * l2e); e[3] = exp2f((v0.w - m) * l2e);
  e[4] = exp2f((v1.x - m) * l2e); e[5] = exp2f((v1.y - m) * l2e);
  e[6] = exp2f((v1.z - m) * l2e); e[7] = exp2f((v1.w - m) * l2e);
  float sum = (e[0] + e[1]) + (e[2] + e[3]) + (e[4] + e[5]) + (e[6] + e[7]);
#pragma unroll
  for (int off = 32; off >= 1; off >>= 1) sum += __shfl_xor(sum, off);
  if ((tid & 63) == 0) red[tid >> 6] = sum;
  __syncthreads();
  float inv = 1.f / (red[0] + red[1] + red[2] + red[3]);
  float4* a4 = (float4*)(alpha + b * T_);
  float4 o0, o1;
  o0.x = e[0] * inv; o0.y = e[1] * inv; o0.z = e[2] * inv; o0.w = e[3] * inv;
  o1.x = e[4] * inv; o1.y = e[5] * inv; o1.z = e[6] * inv; o1.w = e[7] * inv;
  a4[tid * 2] = o0;
  a4[tid * 2 + 1] = o1;
}

// ------------------------------------------------------------- context
// Partial context per 128-t chunk into ctxp[(b*16+bt)][h]; no atomics.
__global__ __launch_bounds__(256) void context_k(const uint4* __restrict__ encA,
                                                 const float* __restrict__ alpha,
                                                 float* __restrict__ ctxp) {
  const int tx = threadIdx.x & 127, th = threadIdx.x >> 7;
  const int b = blockIdx.y, bt = blockIdx.x;
  const int mt = b * 16 + bt;
  const uint4* base = encA + ((size_t)mt * 128 + tx) * 128 + th * 64;
  const float* al = alpha + b * T_ + bt * 128 + th * 64;
  float a[8];
#pragma unroll
  for (int j = 0; j < 8; ++j) a[j] = 0.f;
#pragma unroll 4
  for (int i = 0; i < 64; ++i) {
    float w = al[i];
    uint4 e = base[i];
    a[0] = fmaf(w, b2f((unsigned short)e.x), a[0]);
    a[1] = fmaf(w, b2f((unsigned short)(e.x >> 16)), a[1]);
    a[2] = fmaf(w, b2f((unsigned short)e.y), a[2]);
    a[3] = fmaf(w, b2f((unsigned short)(e.y >> 16)), a[3]);
    a[4] = fmaf(w, b2f((unsigned short)e.z), a[4]);
    a[5] = fmaf(w, b2f((unsigned short)(e.z >> 16)), a[5]);
    a[6] = fmaf(w, b2f((unsigned short)e.w), a[6]);
    a[7] = fmaf(w, b2f((unsigned short)(e.w >> 16)), a[7]);
  }
  __shared__ float cred[2][128][8];
#pragma unroll
  for (int j = 0; j < 8; ++j) cred[th][tx][j] = a[j];
  __syncthreads();
  if (th == 0) {
    float* o = ctxp + (size_t)mt * H_ + tx * 8;
#pragma unroll
    for (int j = 0; j < 8; ++j) o[j] = cred[0][tx][j] + cred[1][tx][j];
  }
}

// Final reduce: out[b,h] = sum_bt ctxp[b*16+bt][h]
__global__ __launch_bounds__(256) void ctx_red_k(const float* __restrict__ ctxp,
                                                 float* __restrict__ out) {
  int id = blockIdx.x * 256 + threadIdx.x;  // 32768 = B*H
  int b = id >> 10, h = id & 1023;
  float s = 0.f;
#pragma unroll
  for (int bt = 0; bt < 16; ++bt) s += ctxp[((size_t)(b * 16 + bt)) * H_ + h];
  out[id] = s;
}

// ------------------------------------------------------------- launch
extern "C" void kernel_launch(void* const* d_in, const int* in_sizes, int n_in,
                              void* d_out, int out_size, void* d_ws, size_t ws_size,
                              hipStream_t stream) {
  const float* enc = (const float*)d_in[0];
  const float* dh  = (const float*)d_in[1];
  const float* Wa  = (const float*)d_in[2];
  const float* Ua  = (const float*)d_in[3];
  const float* Va  = (const float*)d_in[4];

  char* ws = (char*)d_ws;
  unsigned short* encA = (unsigned short*)ws;                     // 128 MiB
  unsigned short* Ub   = (unsigned short*)(ws + 134217728);       // 2 MiB
  float* dp4    = (float*)(ws + 136314880);                       // 512 KiB
  float* score8 = (float*)(ws + 136839168);                       // 2 MiB
  float* alpha  = dp4;     // overlay: dp4 dead after score_gemm
  float* ctxp   = score8;  // overlay: score8 dead after softmax

  conv_enc_k<<<4096, 256, 0, stream>>>((const float4*)enc, (uint4*)encA);
  conv_ua_k<<<4096, 256, 0, stream>>>(Ua, Ub);
  decproj_k<<<dim3(4, 32, 4), 256, 0, stream>>>(dh, Wa, dp4);
  score_gemm_k<<<4096, 256, 0, stream>>>(encA, Ub, dp4, Va, score8);
  softmax_k<<<32, 256, 0, stream>>>(score8, alpha);
  context_k<<<dim3(16, 32), 256, 0, stream>>>((const uint4*)encA, alpha, ctxp);
  ctx_red_k<<<128, 256, 0, stream>>>(ctxp, (float*)d_out);
}

// Round 4
// 560.548 us; speedup vs baseline: 1.2375x; 1.0454x over previous
//
#include <hip/hip_runtime.h>
#include <stdint.h>

// Bahdanau additive attention, MI355X (gfx950).
// B=32, T=2048, H=1024, U=1024. All inputs fp32; output context [B,H] fp32.
//
// R4 changes vs R3:
//  - score_gemm XCD-aware swizzle: bx = (s<<6)|(m3<<3)|x -> mtile = s*8+x,
//    ntile = m3. Round-robin dispatch puts all 8 ntile-blocks of an mtile on
//    ONE XCD, back-to-back: A-tile L2-resident (7/8 staging passes hit L2),
//    encA HBM fetch drops to the 128 MB compulsory read.
//  - conv_ua: dense 16B packed writes (one thread = 8 h of one u).

#define B_ 32
#define T_ 2048
#define H_ 1024
#define U_ 1024
#define M_ (B_ * T_)

typedef __bf16 bf16x8 __attribute__((ext_vector_type(8)));
typedef float f32x4 __attribute__((ext_vector_type(4)));

__device__ __forceinline__ unsigned f2b(float f) {  // fp32 -> bf16 bits, RNE
  unsigned u = __float_as_uint(f);
  return (u + 0x7FFFu + ((u >> 16) & 1u)) >> 16;
}
__device__ __forceinline__ float b2f(unsigned short u) {
  return __uint_as_float(((unsigned)u) << 16);
}
__device__ __forceinline__ float fast_tanh(float x) {
  float xc = fminf(fmaxf(x, -12.f), 12.f);
  float t = exp2f(xc * 2.885390081777927f);  // 2*log2(e)
  return (t - 1.f) * __builtin_amdgcn_rcpf(t + 1.f);
}

#define AS1 __attribute__((address_space(1)))
#define AS3 __attribute__((address_space(3)))
__device__ __forceinline__ void gld_lds16(const void* g, void* l) {
  __builtin_amdgcn_global_load_lds((AS1 const void*)g, (AS3 void*)l, 16, 0, 0);
}

// ------------------------------------------------------------- conv_enc
// enc fp32 [M][1024] -> encA bf16 packed [mt][k8][ml][8] via LDS transpose.
// Reads fully sequential 32B/lane; LDS stride-17 uint4 (conflict-free both
// phases); writes 4 x 256B segments per wave instruction.
__global__ __launch_bounds__(256) void conv_enc_k(const float4* __restrict__ in,
                                                  uint4* __restrict__ outA) {
  __shared__ uint4 L4[128 * 17];
  const int tx = threadIdx.x;
  const int band = blockIdx.x;      // 0..4095
  const int mt = band >> 3;
  const int R = (band & 7) << 4;    // ml base within 128-row tile
  const float4* src = in + (size_t)band * 4096;  // 16 rows * 256 float4
#pragma unroll
  for (int i = 0; i < 8; ++i) {
    int p = i * 256 + tx;           // pair index: row r, k8 chunk pc
    int r = p >> 7, pc = p & 127;
    float4 a = src[r * 256 + pc * 2];
    float4 b = src[r * 256 + pc * 2 + 1];
    uint4 o;
    o.x = f2b(a.x) | (f2b(a.y) << 16);
    o.y = f2b(a.z) | (f2b(a.w) << 16);
    o.z = f2b(b.x) | (f2b(b.y) << 16);
    o.w = f2b(b.z) | (f2b(b.w) << 16);
    L4[pc * 17 + r] = o;
  }
  __syncthreads();
  const int r2 = tx & 15, kq = (tx >> 4) & 3, w = tx >> 6;
#pragma unroll
  for (int j = 0; j < 8; ++j) {
    int k8 = j * 16 + w * 4 + kq;
    outA[((size_t)mt * 128 + k8) * 128 + R + r2] = L4[k8 * 17 + r2];
  }
}

// Ua [H][U] fp32 -> Ub [(H/8)][U][8] bf16, dense 16B writes.
// Thread (h8,u): reads 8 rows (coalesced across u), writes one uint4.
__global__ __launch_bounds__(256) void conv_ua_k(const float* __restrict__ in,
                                                 uint4* __restrict__ out) {
  int id = blockIdx.x * 256 + threadIdx.x;  // 131072 = 128 h8 * 1024 u
  int h8 = id >> 10, u = id & 1023;
  const float* p = in + (size_t)(h8 << 3) * U_ + u;
  uint4 o;
  o.x = f2b(p[0]) | (f2b(p[U_]) << 16);
  o.y = f2b(p[2 * U_]) | (f2b(p[3 * U_]) << 16);
  o.z = f2b(p[4 * U_]) | (f2b(p[5 * U_]) << 16);
  o.w = f2b(p[6 * U_]) | (f2b(p[7 * U_]) << 16);
  out[(size_t)h8 * U_ + u] = o;
}

// ------------------------------------------------------------- dec_proj
// dp4[hz][b][u] = partial over 256-h chunk; no atomics, no memset.
__global__ __launch_bounds__(256) void decproj_k(const float* __restrict__ dh,
                                                 const float* __restrict__ Wa,
                                                 float* __restrict__ dp4) {
  const int u = blockIdx.x * 256 + threadIdx.x;
  const int b = blockIdx.y, hz = blockIdx.z;
  const float* d = dh + b * H_ + hz * 256;
  const float* w = Wa + (size_t)(hz * 256) * U_ + u;
  float a0 = 0.f, a1 = 0.f, a2 = 0.f, a3 = 0.f;
#pragma unroll 4
  for (int h = 0; h < 256; h += 4) {
    a0 = fmaf(d[h + 0], w[(size_t)(h + 0) * U_], a0);
    a1 = fmaf(d[h + 1], w[(size_t)(h + 1) * U_], a1);
    a2 = fmaf(d[h + 2], w[(size_t)(h + 2) * U_], a2);
    a3 = fmaf(d[h + 3], w[(size_t)(h + 3) * U_], a3);
  }
  dp4[((hz * B_ + b) * U_) + u] = (a0 + a1) + (a2 + a3);
}

// ------------------------------------------------------------- fused GEMM
// XCD swizzle: bx = (s<<6)|(m3<<3)|x  ->  mtile = s*8+x, ntile = m3.
// Round-robin XCD dispatch => the 8 ntile-blocks of one mtile run
// consecutively on one XCD; A-tile (256 KiB) stays in that XCD's L2.
__global__ __launch_bounds__(256, 2) void score_gemm_k(
    const unsigned short* __restrict__ encA,  // packed [mt][k8][ml][8]
    const unsigned short* __restrict__ Ub,    // [k8][N][8]
    const float* __restrict__ dp4,            // [4][B][U]
    const float* __restrict__ Va,             // [U]
    float* __restrict__ score8)               // [8][M]
{
  __shared__ union {
    struct {
      alignas(16) unsigned short As[8][128][8];  // [k8][m][j] 16 KiB
      alignas(16) unsigned short Bs[8][128][8];  // [k8][n][j] 16 KiB
    } t;
    float sred[128 * 33];  // epilogue scratch, stride-33 pad
  } sm;

  const int bx = blockIdx.x;
  const int mtile = ((bx >> 6) << 3) | (bx & 7), ntile = (bx >> 3) & 7;
  const int m0 = mtile << 7, n0 = ntile << 7;
  const int tid = threadIdx.x;
  const int wv = tid >> 6, ln = tid & 63;
  const int wm = wv & 1, wn = wv >> 1;
  const int quad = ln >> 4, l16 = ln & 15;

  f32x4 acc[4][4];
  const f32x4 zero = {0.f, 0.f, 0.f, 0.f};
#pragma unroll
  for (int i = 0; i < 4; ++i)
#pragma unroll
    for (int j = 0; j < 4; ++j) acc[i][j] = zero;

  const unsigned short* encT = encA + (size_t)mtile * (128 * 128 * 8);

  for (int k0 = 0; k0 < H_; k0 += 64) {
    __syncthreads();
#pragma unroll
    for (int c = 0; c < 4; ++c) {
      int chunk = (wv << 2) + c;  // 0..15
      int k8 = chunk >> 1, half = chunk & 1;
      const unsigned short* ga =
          encT + (((size_t)((k0 >> 3) + k8) * 128) + (half << 6) + ln) * 8;
      gld_lds16(ga, &sm.t.As[k8][half << 6][0]);
      const unsigned short* gb =
          Ub + (((size_t)((k0 >> 3) + k8) * U_) + n0 + (half << 6) + ln) * 8;
      gld_lds16(gb, &sm.t.Bs[k8][half << 6][0]);
    }
    __syncthreads();

#pragma unroll
    for (int kk = 0; kk < 2; ++kk) {
      int k8b = (kk << 2) + quad;
      bf16x8 af[4], bf[4];
#pragma unroll
      for (int mt = 0; mt < 4; ++mt)
        af[mt] = *(const bf16x8*)&sm.t.As[k8b][(wm << 6) + (mt << 4) + l16][0];
#pragma unroll
      for (int nt = 0; nt < 4; ++nt)
        bf[nt] = *(const bf16x8*)&sm.t.Bs[k8b][(wn << 6) + (nt << 4) + l16][0];
#pragma unroll
      for (int mt = 0; mt < 4; ++mt)
#pragma unroll
        for (int nt = 0; nt < 4; ++nt)
          acc[mt][nt] = __builtin_amdgcn_mfma_f32_16x16x32_bf16(
              af[mt], bf[nt], acc[mt][nt], 0, 0, 0);
    }
  }

  // Epilogue: v = sum_nt tanh(acc + dp) * Va; LDS reduce over 32 col-groups.
  // C/D layout: col = l16, row = quad*4 + r.
  const int bq = m0 >> 11;  // batch (tile never straddles b)
  float va[4], dpv[4];
#pragma unroll
  for (int nt = 0; nt < 4; ++nt) {
    int col = n0 + (wn << 6) + (nt << 4) + l16;
    va[nt] = Va[col];
    dpv[nt] = dp4[bq * U_ + col] + dp4[B_ * U_ + bq * U_ + col] +
              dp4[2 * B_ * U_ + bq * U_ + col] + dp4[3 * B_ * U_ + bq * U_ + col];
  }
  __syncthreads();  // LDS tile reads done; reuse as sred
#pragma unroll
  for (int mt = 0; mt < 4; ++mt) {
#pragma unroll
    for (int r = 0; r < 4; ++r) {
      float v = 0.f;
#pragma unroll
      for (int nt = 0; nt < 4; ++nt)
        v += fast_tanh(acc[mt][nt][r] + dpv[nt]) * va[nt];
      int row = (wm << 6) + (mt << 4) + (quad << 2) + r;
      sm.sred[row * 33 + (wn << 4) + l16] = v;
    }
  }
  __syncthreads();
  if (tid < 128) {
    const float* p = &sm.sred[tid * 33];
    float s = 0.f;
#pragma unroll
    for (int j = 0; j < 32; ++j) s += p[j];
    score8[(size_t)ntile * M_ + m0 + tid] = s;
  }
}

// ------------------------------------------------------------- softmax
// Sums the 8 ntile slabs, then softmax over T per b; writes alpha.
__global__ __launch_bounds__(256) void softmax_k(const float* __restrict__ score8,
                                                 float* __restrict__ alpha) {
  const int b = blockIdx.x, tid = threadIdx.x;
  __shared__ float red[4];
  float4 v0 = {0.f, 0.f, 0.f, 0.f}, v1 = {0.f, 0.f, 0.f, 0.f};
#pragma unroll
  for (int k = 0; k < 8; ++k) {
    const float4* p = (const float4*)(score8 + (size_t)k * M_ + b * T_);
    float4 x0 = p[tid * 2], x1 = p[tid * 2 + 1];
    v0.x += x0.x; v0.y += x0.y; v0.z += x0.z; v0.w += x0.w;
    v1.x += x1.x; v1.y += x1.y; v1.z += x1.z; v1.w += x1.w;
  }
  float m = fmaxf(fmaxf(fmaxf(v0.x, v0.y), fmaxf(v0.z, v0.w)),
                  fmaxf(fmaxf(v1.x, v1.y), fmaxf(v1.z, v1.w)));
#pragma unroll
  for (int off = 32; off >= 1; off >>= 1) m = fmaxf(m, __shfl_xor(m, off));
  if ((tid & 63) == 0) red[tid >> 6] = m;
  __syncthreads();
  m = fmaxf(fmaxf(red[0], red[1]), fmaxf(red[2], red[3]));
  __syncthreads();
  const float l2e = 1.4426950408889634f;
  float e[8];
  e[0] = exp2f((v0.x - m) * l2e); e[1] = exp2f((v0.y - m) * l2e);
  e[2] = exp2f((v0.z - m) * l2e); e[3] = exp2f((v0.w - m) * l2e);
  e[4] = exp2f((v1.x - m) * l2e); e[5] = exp2f((v1.y - m) * l2e);
  e[6] = exp2f((v1.z - m) * l2e); e[7] = exp2f((v1.w - m) * l2e);
  float sum = (e[0] + e[1]) + (e[2] + e[3]) + (e[4] + e[5]) + (e[6] + e[7]);
#pragma unroll
  for (int off = 32; off >= 1; off >>= 1) sum += __shfl_xor(sum, off);
  if ((tid & 63) == 0) red[tid >> 6] = sum;
  __syncthreads();
  float inv = 1.f / (red[0] + red[1] + red[2] + red[3]);
  float4* a4 = (float4*)(alpha + b * T_);
  float4 o0, o1;
  o0.x = e[0] * inv; o0.y = e[1] * inv; o0.z = e[2] * inv; o0.w = e[3] * inv;
  o1.x = e[4] * inv; o1.y = e[5] * inv; o1.z = e[6] * inv; o1.w = e[7] * inv;
  a4[tid * 2] = o0;
  a4[tid * 2 + 1] = o1;
}

// ------------------------------------------------------------- context
// Partial context per 128-t chunk into ctxp[(b*16+bt)][h]; no atomics.
__global__ __launch_bounds__(256) void context_k(const uint4* __restrict__ encA,
                                                 const float* __restrict__ alpha,
                                                 float* __restrict__ ctxp) {
  const int tx = threadIdx.x & 127, th = threadIdx.x >> 7;
  const int b = blockIdx.y, bt = blockIdx.x;
  const int mt = b * 16 + bt;
  const uint4* base = encA + ((size_t)mt * 128 + tx) * 128 + th * 64;
  const float* al = alpha + b * T_ + bt * 128 + th * 64;
  float a[8];
#pragma unroll
  for (int j = 0; j < 8; ++j) a[j] = 0.f;
#pragma unroll 4
  for (int i = 0; i < 64; ++i) {
    float w = al[i];
    uint4 e = base[i];
    a[0] = fmaf(w, b2f((unsigned short)e.x), a[0]);
    a[1] = fmaf(w, b2f((unsigned short)(e.x >> 16)), a[1]);
    a[2] = fmaf(w, b2f((unsigned short)e.y), a[2]);
    a[3] = fmaf(w, b2f((unsigned short)(e.y >> 16)), a[3]);
    a[4] = fmaf(w, b2f((unsigned short)e.z), a[4]);
    a[5] = fmaf(w, b2f((unsigned short)(e.z >> 16)), a[5]);
    a[6] = fmaf(w, b2f((unsigned short)e.w), a[6]);
    a[7] = fmaf(w, b2f((unsigned short)(e.w >> 16)), a[7]);
  }
  __shared__ float cred[2][128][8];
#pragma unroll
  for (int j = 0; j < 8; ++j) cred[th][tx][j] = a[j];
  __syncthreads();
  if (th == 0) {
    float* o = ctxp + (size_t)mt * H_ + tx * 8;
#pragma unroll
    for (int j = 0; j < 8; ++j) o[j] = cred[0][tx][j] + cred[1][tx][j];
  }
}

// Final reduce: out[b,h] = sum_bt ctxp[b*16+bt][h]
__global__ __launch_bounds__(256) void ctx_red_k(const float* __restrict__ ctxp,
                                                 float* __restrict__ out) {
  int id = blockIdx.x * 256 + threadIdx.x;  // 32768 = B*H
  int b = id >> 10, h = id & 1023;
  float s = 0.f;
#pragma unroll
  for (int bt = 0; bt < 16; ++bt) s += ctxp[((size_t)(b * 16 + bt)) * H_ + h];
  out[id] = s;
}

// ------------------------------------------------------------- launch
extern "C" void kernel_launch(void* const* d_in, const int* in_sizes, int n_in,
                              void* d_out, int out_size, void* d_ws, size_t ws_size,
                              hipStream_t stream) {
  const float* enc = (const float*)d_in[0];
  const float* dh  = (const float*)d_in[1];
  const float* Wa  = (const float*)d_in[2];
  const float* Ua  = (const float*)d_in[3];
  const float* Va  = (const float*)d_in[4];

  char* ws = (char*)d_ws;
  unsigned short* encA = (unsigned short*)ws;                     // 128 MiB
  unsigned short* Ub   = (unsigned short*)(ws + 134217728);       // 2 MiB
  float* dp4    = (float*)(ws + 136314880);                       // 512 KiB
  float* score8 = (float*)(ws + 136839168);                       // 2 MiB
  float* alpha  = dp4;     // overlay: dp4 dead after score_gemm
  float* ctxp   = score8;  // overlay: score8 dead after softmax

  conv_enc_k<<<4096, 256, 0, stream>>>((const float4*)enc, (uint4*)encA);
  conv_ua_k<<<512, 256, 0, stream>>>(Ua, (uint4*)Ub);
  decproj_k<<<dim3(4, 32, 4), 256, 0, stream>>>(dh, Wa, dp4);
  score_gemm_k<<<4096, 256, 0, stream>>>(encA, Ub, dp4, Va, score8);
  softmax_k<<<32, 256, 0, stream>>>(score8, alpha);
  context_k<<<dim3(16, 32), 256, 0, stream>>>((const uint4*)encA, alpha, ctxp);
  ctx_red_k<<<128, 256, 0, stream>>>(ctxp, (float*)d_out);
}